// Round 4
// baseline (2523.766 us; speedup 1.0000x reference)
//
#include <hip/hip_runtime.h>
#include <cstdint>
#include <cstddef>

// Problem constants
#define NB    64      // batch
#define NS    4096    // seq len
#define NH    1024    // hidden
#define NOPSN 8
#define NSTEP 10

#define GRID  256
#define TPB   1024    // 16 waves/block, 1 block/CU -> 4 waves/SIMD

// Workspace layout (float offsets), ~7.2 MB.
// Cross-block mutable data is STEP-ROTATED: each step writes a fresh buffer
// (device-scope sc1 stores, bypassing L2) and readers use normal cached
// loads on first-touch addresses -> never stale in any L2 -> NO cache
// fences needed at grid barriers -> weights stay L2-resident across steps.
#define OFF_HN   0u          // hn  [10][64][1024]
#define OFF_HNT  655360u     // hnT [10][512][128] (k-pair interleave)
#define OFF_H    1310720u    // h   [64][1024]  (block-private across steps)
#define OFF_CAND 1376256u    // cand [10][64][256] float2 (val, idx)
#define OFF_OPP  1703936u    // opp [10][16 jg][64 b][8 o]
#define OFF_CTRL 1785856u    // ints: [0]=magic [1]=barrier cnt [2..11]=stopcnt[t]
#define MAGIC    0x1357A5E5

typedef float f2v  __attribute__((ext_vector_type(2)));
typedef float f4v  __attribute__((ext_vector_type(4)));
typedef float f16v __attribute__((ext_vector_type(16)));

__device__ __forceinline__ float bcastf(float v, int l) {
  return __int_as_float(__builtin_amdgcn_readlane(__float_as_int(v), l));
}
// device-scope (sc1) relaxed stores: write-through to coherence point
__device__ __forceinline__ void stf(float* p, float v) {
  __hip_atomic_store((int*)p, __float_as_int(v), __ATOMIC_RELAXED, __HIP_MEMORY_SCOPE_AGENT);
}
__device__ __forceinline__ void stf2(float2* p, float2 v) {
  union { float2 f; unsigned long long u; } cv; cv.f = v;
  __hip_atomic_store((unsigned long long*)p, cv.u, __ATOMIC_RELAXED, __HIP_MEMORY_SCOPE_AGENT);
}

// Fence-free grid barrier. __syncthreads() drains each wave's vmem
// (compiler emits s_waitcnt vmcnt(0) before s_barrier) -> all sc1 stores
// are at the coherence point before the arrival add. No wbl2/inv.
__device__ __forceinline__ void gridbar(int* cnt, int target) {
  __syncthreads();
  if (threadIdx.x == 0) {
    asm volatile("" ::: "memory");
    __hip_atomic_fetch_add(cnt, 1, __ATOMIC_RELAXED, __HIP_MEMORY_SCOPE_AGENT);
    while (__hip_atomic_load(cnt, __ATOMIC_RELAXED, __HIP_MEMORY_SCOPE_AGENT) < target)
      __builtin_amdgcn_s_sleep(1);
    asm volatile("" ::: "memory");
  }
  __syncthreads();
}

__global__ void __launch_bounds__(TPB, 4)
sys1_kernel(const float* __restrict__ s2a,  const float* __restrict__ Wres,
            const float* __restrict__ bres, const float* __restrict__ Wop,
            const float* __restrict__ bop,  const float* __restrict__ Wx,
            const float* __restrict__ bx,   const float* __restrict__ noise,
            float* __restrict__ out,        float* __restrict__ wsf)
{
  __shared__ float smem[16384];   // 64 KB: cross-wave reductions only

  float* __restrict__ h   = wsf + OFF_H;
  float* __restrict__ opp = wsf + OFF_OPP;
  int* ctrl = (int*)(wsf + OFF_CTRL);
  int* cnt  = ctrl + 1;

  const int tid = threadIdx.x;
  const int blk = blockIdx.x;

  // ---- bootstrap: block 0 inits ctrl (ws is poisoned every launch) ----
  if (blk == 0 && tid == 0) {
    #pragma unroll
    for (int i = 1; i < 32; ++i) ctrl[i] = 0;
    __threadfence();
    __hip_atomic_store(&ctrl[0], (int)MAGIC, __ATOMIC_RELEASE, __HIP_MEMORY_SCOPE_AGENT);
  }
  if (tid == 0) {
    while (__hip_atomic_load(&ctrl[0], __ATOMIC_RELAXED, __HIP_MEMORY_SCOPE_AGENT) != (int)MAGIC)
      __builtin_amdgcn_s_sleep(1);
  }
  __syncthreads();

  const int lane = tid & 63;
  const int wv   = __builtin_amdgcn_readfirstlane(tid >> 6);   // wave 0..15

  // ---- INIT: hn(0)=0.01*noise[0] (sc1), hnT(0) (sc1), h=0, oppart[0] (sc1) ----
  {
    const int jg = blk & 15, bg = blk >> 4;
    if (tid < 256) {
      const int bsel = tid >> 6, jloc = tid & 63;
      const int b = bg * 4 + bsel, j = jg * 64 + jloc;
      float hv = 0.01f * noise[(size_t)b * NH + j];
      stf(wsf + OFF_HN  + (size_t)b * NH + j, hv);
      stf(wsf + OFF_HNT + ((size_t)(j >> 1)) * 128 + b * 2 + (j & 1), hv);
      h[(size_t)b * NH + j] = 0.f;
      const float* wr = Wop + (size_t)j * NOPSN;
      float opo[8];
      #pragma unroll
      for (int o = 0; o < 8; ++o) opo[o] = hv * wr[o];
      #pragma unroll
      for (int off = 1; off <= 32; off <<= 1) {
        #pragma unroll
        for (int o = 0; o < 8; ++o) opo[o] += __shfl_xor(opo[o], off);
      }
      if (lane == 0) {
        float* od = opp + (size_t)jg * 512 + (size_t)b * 8;
        #pragma unroll
        for (int o = 0; o < 8; ++o) stf(&od[o], opo[o]);
      }
    }
  }
  int ep = 0;
  gridbar(cnt, ++ep * GRID);

  for (int st = 0; st < NSTEP; ++st) {
    const float* __restrict__ hn_cur  = wsf + OFF_HN  + (size_t)st * (NB * NH);
    float* __restrict__       hn_nxt  = wsf + OFF_HN  + (size_t)(st + 1) * (NB * NH);
    const float* __restrict__ hnT_cur = wsf + OFF_HNT + (size_t)st * (NB * NH);
    float* __restrict__       hnT_nxt = wsf + OFF_HNT + (size_t)(st + 1) * (NB * NH);
    float2* __restrict__      cand_st = (float2*)(wsf + OFF_CAND) + (size_t)st * (NB * 256);

    // ================= PHASE A =================
    // Block: x_logits[16 s][64 b], full K=1024. lane = b.
    // Weights per-lane: lane l holds Wx[kbase+l][s0..s0+15] (one f16v load
    // fetches the wave's whole 16KB weight slice in parallel), broadcast
    // per-k via v_readlane. h batch-loaded in register chunks.
    {
      const int s0 = blk << 4;
      const int kbase = wv << 6;                    // wave's 64 k
      const f16v wreg = *(const f16v*)(Wx + (size_t)(kbase + lane) * NS + s0);
      const float2* hb = (const float2*)hnT_cur + ((size_t)(kbase >> 1)) * 64 + lane;

      float2 hA[8], hB[8];
      #pragma unroll
      for (int i = 0; i < 8; ++i) hA[i] = hb[(size_t)i * 64];
      #pragma unroll
      for (int i = 0; i < 8; ++i) hB[i] = hb[(size_t)(8 + i) * 64];

      // op-argmax for step st (blocks 0..63, wave 0) — overlaps the loads
      if (blk < NB && tid < 64) {
        const float* ob = opp + (size_t)st * 8192 + (size_t)blk * 8;
        const int o = lane & 7, jgb = lane >> 3;
        float v = ob[(size_t)jgb * 512 + o] + ob[(size_t)(jgb + 8) * 512 + o];
        v += __shfl_xor(v, 8);
        v += __shfl_xor(v, 16);
        v += __shfl_xor(v, 32);
        v += bop[o];
        float bv = bcastf(v, 0); int bo = 0;
        #pragma unroll
        for (int oo = 1; oo < 8; ++oo) {
          float vo = bcastf(v, oo);
          if (vo > bv) { bv = vo; bo = oo; }        // strict > : first-max
        }
        if (lane == 0 && bo == 0) atomicAdd(&ctrl[2 + st], 1);
      }

      f2v acc[8];
      #pragma unroll
      for (int i = 0; i < 8; ++i) acc[i] = (f2v){0.f, 0.f};

#define CHUNKA(HREG, KP0)                                                   \
      _Pragma("unroll")                                                     \
      for (int i = 0; i < 8; ++i) {                                         \
        const float2 hc = HREG[i];                                          \
        _Pragma("unroll")                                                   \
        for (int s = 0; s < 8; ++s) {                                       \
          f2v w0 = { bcastf(wreg[2*s], 2*((KP0)+i)),                        \
                     bcastf(wreg[2*s+1], 2*((KP0)+i)) };                    \
          f2v w1 = { bcastf(wreg[2*s], 2*((KP0)+i)+1),                      \
                     bcastf(wreg[2*s+1], 2*((KP0)+i)+1) };                  \
          acc[s] += w0 * hc.x;                                              \
          acc[s] += w1 * hc.y;                                              \
        }                                                                   \
      }

      CHUNKA(hA, 0)
      #pragma unroll
      for (int i = 0; i < 8; ++i) hA[i] = hb[(size_t)(16 + i) * 64];
      CHUNKA(hB, 8)
      #pragma unroll
      for (int i = 0; i < 8; ++i) hB[i] = hb[(size_t)(24 + i) * 64];
      CHUNKA(hA, 16)
      CHUNKA(hB, 24)
#undef CHUNKA

      // cross-wave K reduction: red[16 w][16 s][64 b]
      #pragma unroll
      for (int s = 0; s < 8; ++s) {
        smem[wv * 1024 + (2 * s) * 64 + lane]     = acc[s].x;
        smem[wv * 1024 + (2 * s + 1) * 64 + lane] = acc[s].y;
      }
      __syncthreads();
      {
        const int s = tid >> 6, b = tid & 63;
        float val = bx[s0 + s];
        #pragma unroll
        for (int w = 0; w < 16; ++w) val += smem[w * 1024 + s * 64 + b];
        __syncthreads();
        smem[s * 64 + b] = val;
        __syncthreads();
        if (tid < 64) {
          const int bb = tid;
          float bv = smem[bb]; int bs = 0;
          #pragma unroll
          for (int s2 = 1; s2 < 16; ++s2) {
            float v2 = smem[s2 * 64 + bb];
            if (v2 > bv) { bv = v2; bs = s2; }      // ascending s: first-max
          }
          stf2(&cand_st[(size_t)bb * 256 + blk],
               make_float2(bv, __int_as_float(s0 + bs)));
        }
      }
    }
    gridbar(cnt, ++ep * GRID);

    // ================= PHASE C =================
    // Block (jg: 64 j, bg: 4 b): h_new full K=2048. lane = j.
    // 8 chunks of 16 k: batch-issue 16 per-lane w loads + 16 wave-uniform
    // f4v h loads, one wait, 64 FMAs (1 instr/MAC).
    {
      const int jg = blk & 15, bg = blk >> 4;
      const int j0 = jg << 6, b0 = bg << 2;

      int ptrs[4] = {0, 0, 0, 0};
      if (wv >= 8) {                                 // only s2a-half needs ptrs
        #pragma unroll
        for (int i = 0; i < 4; ++i) {
          const float2* row = cand_st + (size_t)(b0 + i) * 256;
          float2 c0 = row[lane];
          float bv = c0.x; int bi = __float_as_int(c0.y);
          #pragma unroll
          for (int q = 1; q < 4; ++q) {
            float2 c = row[q * 64 + lane];
            if (c.x > bv) { bv = c.x; bi = __float_as_int(c.y); }
          }
          #pragma unroll
          for (int off = 1; off <= 32; off <<= 1) {
            float ov = __shfl_xor(bv, off);
            int   oi = __shfl_xor(bi, off);
            if (ov > bv || (ov == bv && oi < bi)) { bv = ov; bi = oi; }
          }
          ptrs[i] = __builtin_amdgcn_readfirstlane(bi);
        }
      }
      int done = 0;
      if (wv < 4) {                                  // only epilogue waves need it
        for (int tt = 0; tt < st; ++tt)
          done |= (__hip_atomic_load(&ctrl[2 + tt], __ATOMIC_RELAXED,
                                     __HIP_MEMORY_SCOPE_AGENT) == NB) ? 1 : 0;
      }

      const int kb = wv << 7;                        // 128 k per wave
      const float *p0, *p1, *p2, *p3;                // wave-uniform bases
      if (wv < 8) {
        p0 = hn_cur + (size_t)(b0 + 0) * NH + kb;
        p1 = hn_cur + (size_t)(b0 + 1) * NH + kb;
        p2 = hn_cur + (size_t)(b0 + 2) * NH + kb;
        p3 = hn_cur + (size_t)(b0 + 3) * NH + kb;
      } else {
        p0 = s2a + ((size_t)(b0 + 0) * NS + ptrs[0]) * NH + (kb - NH);
        p1 = s2a + ((size_t)(b0 + 1) * NS + ptrs[1]) * NH + (kb - NH);
        p2 = s2a + ((size_t)(b0 + 2) * NS + ptrs[2]) * NH + (kb - NH);
        p3 = s2a + ((size_t)(b0 + 3) * NS + ptrs[3]) * NH + (kb - NH);
      }
      const float* wp = Wres + (size_t)kb * NH + j0 + lane;   // per-lane

      float a0 = 0.f, a1 = 0.f, a2 = 0.f, a3 = 0.f;

#define CCHUNK(K0)                                                          \
      {                                                                     \
        float wr[16]; f4v q0[4], q1[4], q2[4], q3[4];                       \
        _Pragma("unroll")                                                   \
        for (int i = 0; i < 16; ++i) wr[i] = wp[(size_t)((K0) + i) * NH];   \
        _Pragma("unroll")                                                   \
        for (int i = 0; i < 4; ++i) {                                       \
          q0[i] = *(const f4v*)(p0 + (K0) + 4 * i);                         \
          q1[i] = *(const f4v*)(p1 + (K0) + 4 * i);                         \
          q2[i] = *(const f4v*)(p2 + (K0) + 4 * i);                         \
          q3[i] = *(const f4v*)(p3 + (K0) + 4 * i);                         \
        }                                                                   \
        _Pragma("unroll")                                                   \
        for (int i = 0; i < 16; ++i) {                                      \
          const float w = wr[i];                                            \
          a0 += q0[i >> 2][i & 3] * w;                                      \
          a1 += q1[i >> 2][i & 3] * w;                                      \
          a2 += q2[i >> 2][i & 3] * w;                                      \
          a3 += q3[i >> 2][i & 3] * w;                                      \
        }                                                                   \
      }

      CCHUNK(0) CCHUNK(16) CCHUNK(32) CCHUNK(48)
      CCHUNK(64) CCHUNK(80) CCHUNK(96) CCHUNK(112)
#undef CCHUNK

      // cross-wave reduce: red[16 w][4 b][64 j]
      smem[wv * 256 + 0 * 64 + lane] = a0;
      smem[wv * 256 + 1 * 64 + lane] = a1;
      smem[wv * 256 + 2 * 64 + lane] = a2;
      smem[wv * 256 + 3 * 64 + lane] = a3;
      __syncthreads();

      if (tid < 256) {
        const int bsel = tid >> 6, jloc = tid & 63;
        float v = bres[j0 + jloc];
        #pragma unroll
        for (int w = 0; w < 16; ++w) v += smem[w * 256 + bsel * 64 + jloc];
        const int b = b0 + bsel, j = j0 + jloc;
        float hold = h[(size_t)b * NH + j];
        float hout = done ? hold : v;
        h[(size_t)b * NH + j] = hout;
        if (st < NSTEP - 1) {
          float hnv = hout + 0.01f * noise[(size_t)(st + 1) * (NB * NH) + (size_t)b * NH + j];
          stf(&hn_nxt[(size_t)b * NH + j], hnv);
          stf(&hnT_nxt[((size_t)(j >> 1)) * 128 + b * 2 + (j & 1)], hnv);
          const float* wr = Wop + (size_t)j * NOPSN;
          float opo[8];
          #pragma unroll
          for (int o = 0; o < 8; ++o) opo[o] = hnv * wr[o];
          #pragma unroll
          for (int off = 1; off <= 32; off <<= 1) {
            #pragma unroll
            for (int o = 0; o < 8; ++o) opo[o] += __shfl_xor(opo[o], off);
          }
          if (lane == 0) {
            float* od = opp + ((size_t)(st + 1) * 16 + jg) * 512 + (size_t)b * 8;
            #pragma unroll
            for (int o = 0; o < 8; ++o) stf(&od[o], opo[o]);
          }
        } else {
          out[(size_t)b * NH + j] = hout;
        }
      }
    }
    if (st < NSTEP - 1) gridbar(cnt, ++ep * GRID);
  }
}

extern "C" void kernel_launch(void* const* d_in, const int* in_sizes, int n_in,
                              void* d_out, int out_size, void* d_ws, size_t ws_size,
                              hipStream_t stream) {
  const float* s2a   = (const float*)d_in[0];
  const float* Wres  = (const float*)d_in[1];
  const float* bres  = (const float*)d_in[2];
  const float* Wop   = (const float*)d_in[3];
  const float* bop   = (const float*)d_in[4];
  const float* Wx    = (const float*)d_in[5];
  const float* bx    = (const float*)d_in[6];
  const float* noise = (const float*)d_in[7];
  float* outp = (float*)d_out;
  float* wsf  = (float*)d_ws;   // needs ~7.2 MB
  hipLaunchKernelGGL(sys1_kernel, dim3(GRID), dim3(TPB), 0, stream,
                     s2a, Wres, bres, Wop, bop, Wx, bx, noise, outp, wsf);
}